// Round 7
// baseline (424.973 us; speedup 1.0000x reference)
//
#include <hip/hip_runtime.h>
#include <stdint.h>

typedef __bf16 bf16;
typedef __bf16 bf16x4 __attribute__((ext_vector_type(4)));
typedef __bf16 bf16x8 __attribute__((ext_vector_type(8)));
typedef float f32x4 __attribute__((ext_vector_type(4)));
typedef float f32x16 __attribute__((ext_vector_type(16)));

#define DM 2048   // embed dim = N = K of GEMMs
#define MM 4096   // B*S rows
#define MFMA16(a, b, c) __builtin_amdgcn_mfma_f32_16x16x32_bf16(a, b, c, 0, 0, 0)
#define MFMA32(a, b, c) __builtin_amdgcn_mfma_f32_32x32x16_bf16(a, b, c, 0, 0, 0)

// counted-vmcnt barrier pair (T4): wait only the N newest-excluded loads.
#define WAITV_BAR(N) asm volatile("s_waitcnt vmcnt(" #N ")\n\ts_barrier" ::: "memory")
#define BAR()        asm volatile("s_barrier" ::: "memory")

__device__ __forceinline__ void gload_lds16(const void* g, void* l) {
  __builtin_amdgcn_global_load_lds((const __attribute__((address_space(1))) uint32_t*)g,
                                   (__attribute__((address_space(3))) uint32_t*)l, 16, 0, 0);
}

// fp32 -> bf16 for x (8.4M) and the 4 weight matrices (4.2M each).
__global__ __launch_bounds__(256) void cvt_f32_bf16(
    const float* __restrict__ s0, const float* __restrict__ s1,
    const float* __restrict__ s2, const float* __restrict__ s3,
    const float* __restrict__ s4,
    bf16* __restrict__ d0, bf16* __restrict__ d1, bf16* __restrict__ d2,
    bf16* __restrict__ d3, bf16* __restrict__ d4)
{
  const size_t i4 = (size_t)(blockIdx.x * 256 + threadIdx.x) * 4;  // float index
  const float* s; bf16* d; size_t off;
  if      (i4 <  8388608u) { s = s0; d = d0; off = i4;             }
  else if (i4 < 12582912u) { s = s1; d = d1; off = i4 -  8388608u; }
  else if (i4 < 16777216u) { s = s2; d = d2; off = i4 - 12582912u; }
  else if (i4 < 20971520u) { s = s3; d = d3; off = i4 - 16777216u; }
  else                     { s = s4; d = d4; off = i4 - 20971520u; }
  const float4 v = *(const float4*)(s + off);
  bf16x4 o = { (bf16)v.x, (bf16)v.y, (bf16)v.z, (bf16)v.w };
  *(bf16x4*)(d + off) = o;
}

// Fused QKV projection — R2 structure (proven 96 us, MfmaUtil 48%): BK=64,
// 2-barrier loop, XOR-swizzled LDS, A staged once for 96 MFMAs/k-step.
// RoPE + softmax-scale fused into Q/K epilogues. V written transposed.
// XCD swizzle: each XCD owns 2 n-columns (3 MB weights L2-resident).
__global__ __launch_bounds__(256, 2) void gemm_qkv_fused(
    const bf16* __restrict__ A,
    const bf16* __restrict__ Wq, const bf16* __restrict__ Wk, const bf16* __restrict__ Wv,
    const float* __restrict__ qb, const float* __restrict__ kb, const float* __restrict__ vb,
    bf16* __restrict__ Cq, bf16* __restrict__ Ck, bf16* __restrict__ Cv)
{
  __shared__ __align__(16) bf16 smem[32768];   // 64 KB
  bf16* As = smem;           // [128][64]
  bf16* Ws = smem + 8192;    // 3 x [128][64]

  const int id = blockIdx.x;               // 512 blocks
  const int xcd = id & 7, jj = id >> 3;
  const int n0 = (xcd * 2 + (jj >> 5)) * 128;
  const int m0 = (jj & 31) * 128;

  const int t = threadIdx.x;
  const int wave = t >> 6, lane = t & 63;
  const int quad = lane >> 4, c16 = lane & 15;
  const int wr = wave >> 1, wc = wave & 1;

  f32x4 acc[3][4][4] = {};

  // staging: granule g=rr*256+t -> LDS row=g>>3, slot=g&7; global column
  // granule = slot ^ (row&7)  (XOR swizzle; permutes within a 128B segment)
  const int srow = t >> 3;
  const int scol = ((t & 7) ^ (srow & 7)) * 8;
  const bf16* gA  = A  + (size_t)(m0 + srow) * DM + scol;
  const bf16* gW0 = Wq + (size_t)(n0 + srow) * DM + scol;
  const bf16* gW1 = Wk + (size_t)(n0 + srow) * DM + scol;
  const bf16* gW2 = Wv + (size_t)(n0 + srow) * DM + scol;

  for (int k0 = 0; k0 < DM; k0 += 64) {
#pragma unroll
    for (int rr = 0; rr < 4; ++rr) {
      const size_t go = (size_t)(rr * 32) * DM;
      const int lo = (rr * 256 + wave * 64) * 8;
      gload_lds16(gA  + go, As + lo);
      gload_lds16(gW0 + go, Ws + lo);
      gload_lds16(gW1 + go, Ws + 8192 + lo);
      gload_lds16(gW2 + go, Ws + 16384 + lo);
    }
    gA += 64; gW0 += 64; gW1 += 64; gW2 += 64;
    __syncthreads();

#pragma unroll
    for (int ks = 0; ks < 2; ++ks) {
      bf16x8 af[4];
#pragma unroll
      for (int i = 0; i < 4; ++i) {
        const int row = wr * 64 + i * 16 + c16;
        const int gi = (ks * 4 + quad) ^ (row & 7);
        af[i] = *(const bf16x8*)&As[row * 64 + gi * 8];
      }
#pragma unroll
      for (int z = 0; z < 3; ++z) {
        bf16x8 bfr[4];
#pragma unroll
        for (int jx = 0; jx < 4; ++jx) {
          const int row = wc * 64 + jx * 16 + c16;
          const int gi = (ks * 4 + quad) ^ (row & 7);
          bfr[jx] = *(const bf16x8*)&Ws[z * 8192 + row * 64 + gi * 8];
        }
#pragma unroll
        for (int i = 0; i < 4; ++i)
#pragma unroll
          for (int jx = 0; jx < 4; ++jx)
            acc[z][i][jx] = MFMA16(af[i], bfr[jx], acc[z][i][jx]);
      }
    }
    __syncthreads();
  }

  // ---- V epilogue: transposed to (B*H, Dh, S), bf16x4 along s ----
  const int h = n0 >> 7;   // one head per 128-wide n-column
#pragma unroll
  for (int jx = 0; jx < 4; ++jx) {
    const int d = wc * 64 + jx * 16 + c16;
    const float bv = vb[n0 + d];
#pragma unroll
    for (int i = 0; i < 4; ++i) {
      const int row = m0 + wr * 64 + i * 16 + quad * 4;
      const int b = row >> 11, s = row & 2047;
      bf16x4 o;
#pragma unroll
      for (int r = 0; r < 4; ++r) o[r] = (bf16)(acc[2][i][jx][r] + bv);
      *(bf16x4*)&Cv[((size_t)((b * 16 + h) * 128 + d)) * 2048 + s] = o;
    }
  }

  // ---- Q/K epilogues: bias + RoPE via LDS round-trip (pair d <-> d+64
  // crosses waves). Q additionally scaled by log2e/sqrt(Dh) for exp2 softmax.
  bf16* Tl = smem;  // [128][136], 34.8 KB, 16B-aligned rows
#pragma unroll
  for (int z = 0; z < 2; ++z) {
    __syncthreads();   // smem free (main loop done / previous z consumed)
#pragma unroll
    for (int jx = 0; jx < 4; ++jx) {
      const int col = wc * 64 + jx * 16 + c16;
      const float bv = (z == 0 ? qb : kb)[n0 + col];
#pragma unroll
      for (int i = 0; i < 4; ++i) {
        const int row = wr * 64 + i * 16 + quad * 4;
#pragma unroll
        for (int r = 0; r < 4; ++r)
          Tl[(row + r) * 136 + col] = (bf16)(acc[z][i][jx][r] + bv);
      }
    }
    __syncthreads();
    bf16* C = (z == 0) ? Cq : Ck;
    const float scale = (z == 0) ? 0.08838834764831845f * 1.4426950408889634f : 1.0f;
#pragma unroll
    for (int rr = 0; rr < 4; ++rr) {
      const int row = rr * 32 + (t >> 3);
      const int d0 = (t & 7) * 8;
      const int s = (m0 + row) & 2047;
      bf16x8 xa = *(const bf16x8*)&Tl[row * 136 + d0];
      bf16x8 xb = *(const bf16x8*)&Tl[row * 136 + d0 + 64];
      bf16x8 o1, o2;
#pragma unroll
      for (int j = 0; j < 8; ++j) {
        const float inv_freq = __expf((float)(d0 + j) * -0.14391156514261228f);
        float sn, cs;
        __sincosf((float)s * inv_freq, &sn, &cs);
        const float a = (float)xa[j], bb = (float)xb[j];
        o1[j] = (bf16)((a * cs - bb * sn) * scale);
        o2[j] = (bf16)((bb * cs + a * sn) * scale);
      }
      *(bf16x8*)&C[(size_t)(m0 + row) * DM + n0 + d0]      = o1;
      *(bf16x8*)&C[(size_t)(m0 + row) * DM + n0 + d0 + 64] = o2;
    }
  }
}

// Output projection GEMM + bias (fp32 out) — R2 structure (BK=64, 2-barrier).
__global__ __launch_bounds__(256, 2) void gemm_bias_f32(
    const bf16* __restrict__ A, const bf16* __restrict__ W,
    const float* __restrict__ bias, float* __restrict__ C)
{
  __shared__ __align__(16) bf16 As[8192];   // [128][64]
  __shared__ __align__(16) bf16 Bs[8192];
  const int id = blockIdx.x;               // 512 blocks
  const int xcd = id & 7, jj = id >> 3;
  const int n0 = (xcd * 2 + (jj >> 5)) * 128;
  const int m0 = (jj & 31) * 128;

  const int t = threadIdx.x;
  const int wave = t >> 6, lane = t & 63;
  const int quad = lane >> 4, c16 = lane & 15;
  const int wr = wave >> 1, wc = wave & 1;

  f32x4 acc[4][4] = {};
  const int srow = t >> 3;
  const int scol = ((t & 7) ^ (srow & 7)) * 8;
  const bf16* gA = A + (size_t)(m0 + srow) * DM + scol;
  const bf16* gB = W + (size_t)(n0 + srow) * DM + scol;

  for (int k0 = 0; k0 < DM; k0 += 64) {
#pragma unroll
    for (int rr = 0; rr < 4; ++rr) {
      const size_t go = (size_t)(rr * 32) * DM;
      const int lo = (rr * 256 + wave * 64) * 8;
      gload_lds16(gA + go, As + lo);
      gload_lds16(gB + go, Bs + lo);
    }
    gA += 64; gB += 64;
    __syncthreads();

#pragma unroll
    for (int ks = 0; ks < 2; ++ks) {
      bf16x8 af[4], bfr[4];
#pragma unroll
      for (int i = 0; i < 4; ++i) {
        const int row = wr * 64 + i * 16 + c16;
        const int gi = (ks * 4 + quad) ^ (row & 7);
        af[i] = *(const bf16x8*)&As[row * 64 + gi * 8];
      }
#pragma unroll
      for (int jx = 0; jx < 4; ++jx) {
        const int row = wc * 64 + jx * 16 + c16;
        const int gi = (ks * 4 + quad) ^ (row & 7);
        bfr[jx] = *(const bf16x8*)&Bs[row * 64 + gi * 8];
      }
#pragma unroll
      for (int i = 0; i < 4; ++i)
#pragma unroll
        for (int jx = 0; jx < 4; ++jx)
          acc[i][jx] = MFMA16(af[i], bfr[jx], acc[i][jx]);
    }
    __syncthreads();
  }

#pragma unroll
  for (int jx = 0; jx < 4; ++jx) {
    const int col = n0 + wc * 64 + jx * 16 + c16;
    const float bv = bias[col];
#pragma unroll
    for (int i = 0; i < 4; ++i) {
      const int row = m0 + wr * 64 + i * 16 + quad * 4;
#pragma unroll
      for (int r = 0; r < 4; ++r)
        C[(size_t)(row + r) * DM + col] = acc[i][jx][r] + bv;
    }
  }
}

// Flash attention v6 = v3 geometry (32q/wave, grid 512, 2 blocks/CU) with
// V moved OUT of the LDS pipeline: PV's A-fragment is 16 contiguous bytes of
// Vt per lane, loaded global->register (L2-resident via XCD pinning; all 4
// waves share the 16 KB tile -> L1). Halves LDS reads, kills the V bank
// conflicts, and decouples PV from the block barrier. K stays in LDS (dbuf
// 32 KB, 4-wave DMA amortization) with counted WAITV_BAR(20) (retires only
// the previous K tile's 4 DMA loads; V + next-K stay in flight). Barrier
// moved up to right after QK^T (last Ks read consumed by MFMA data-dep) so
// softmax+PV cover the next tile's DMA. QK^T rb0/rb1 interleaved for ILP.
__global__ __launch_bounds__(256, 2) void attn(
    const bf16* __restrict__ Q, const bf16* __restrict__ K,
    const bf16* __restrict__ Vt, bf16* __restrict__ O)
{
  __shared__ __align__(16) bf16 Ks[2][64][128];   // [buf][key][dh] 32 KB
  const int t = threadIdx.x;
  const int wave = t >> 6, lane = t & 63;
  const int r31 = lane & 31, h = lane >> 5;
  const int id = blockIdx.x;               // 512 blocks
  const int xcd = id & 7, jj = id >> 3;
  const int bh = xcd * 4 + (jj >> 4);
  const int q0 = (jj & 15) * 128;
  const int b = bh >> 4, hd = bh & 15;

  // Q fragments (B-operand): lane holds Q[q = r31][dh = ks*16 + h*8 + j]
  bf16x8 qf[8];
  {
    const bf16* qrow = Q + (size_t)(b * 2048 + q0 + wave * 32 + r31) * 2048
                         + (size_t)hd * 128 + h * 8;
#pragma unroll
    for (int ks = 0; ks < 8; ++ks) qf[ks] = *(const bf16x8*)(qrow + ks * 16);
  }

  float l_i = 0.f;
  f32x16 o_acc[4] = {};   // O^T[d = db*32 + (reg&3)+8*(reg>>2)+4h][q = r31]

  const bf16* Kg = K + (size_t)(b * 2048) * 2048 + (size_t)hd * 128;
  // per-lane V base: row d = r31 (+db*32 via offset), col h*8 (+kap*16+kt0)
  const bf16* Vlane = Vt + (size_t)bh * 128 * 2048 + (size_t)r31 * 2048 + h * 8;

  auto stageK = [&](int kt0, int nb) {
#pragma unroll
    for (int rr = 0; rr < 4; ++rr) {
      const int G = rr * 256 + t;
      const int key = G >> 4, gl = G & 15;
      gload_lds16(Kg + (size_t)(kt0 + key) * 2048 + ((gl ^ (key & 7)) * 8),
                  (bf16*)Ks[nb] + (rr * 256 + wave * 64) * 8);
    }
  };

  stageK(0, 0);   // 4 DMA loads in flight

  for (int kt = 0; kt < 32; ++kt) {
    const int cb = kt & 1;
    const int kt0 = kt * 64;

    // V tile -> registers: vv[kap*4+db] = V^T[db*32+r31][kt0+kap*16+h*8 ..+8].
    // Issued before the K-wait; consumed after the barrier -> QK^T covers L2
    // latency (compiler inserts exact per-value vmcnt waits before PV).
    bf16x8 vv[16];
#pragma unroll
    for (int kap = 0; kap < 4; ++kap)
#pragma unroll
      for (int db = 0; db < 4; ++db)
        vv[kap * 4 + db] =
            *(const bf16x8*)(Vlane + (size_t)db * 65536 + kt0 + kap * 16);

    if (kt < 31) {
      stageK(kt0 + 64, cb ^ 1);   // +4 DMA into the other buffer
      WAITV_BAR(20);              // retire prev K DMA (4 oldest); V+nextK fly
    } else {
      WAITV_BAR(16);
    }

    // QK^T rb0/rb1 interleaved (independent chains -> 2-way MFMA ILP)
    f32x16 st0 = {}, st1 = {};
#pragma unroll
    for (int ks = 0; ks < 8; ++ks) {
      const int g = (2 * ks + h) ^ (r31 & 7);
      bf16x8 kf0 = *(const bf16x8*)&Ks[cb][r31][g * 8];
      bf16x8 kf1 = *(const bf16x8*)&Ks[cb][32 + r31][g * 8];
      st0 = MFMA32(kf0, qf[ks], st0);
      st1 = MFMA32(kf1, qf[ks], st1);
    }

    BAR();   // all Ks[cb] reads consumed (MFMA data-dep) -> tile reusable;
             // softmax + PV below are register/global-only and overlap the
             // other waves' progress into the next tile's staging.

#pragma unroll
    for (int rb = 0; rb < 2; ++rb) {
      const f32x16& st = (rb == 0) ? st0 : st1;
      float p[16];
#pragma unroll
      for (int r = 0; r < 16; ++r) { p[r] = exp2f(st[r]); l_i += p[r]; }

      uint32_t pka[4], pkb[4];
#pragma unroll
      for (int pp = 0; pp < 4; ++pp) {
        asm("v_cvt_pk_bf16_f32 %0, %1, %2"
            : "=v"(pka[pp]) : "v"(p[4 * pp + 0]), "v"(p[4 * pp + 1]));
        asm("v_cvt_pk_bf16_f32 %0, %1, %2"
            : "=v"(pkb[pp]) : "v"(p[4 * pp + 2]), "v"(p[4 * pp + 3]));
      }
#pragma unroll
      for (int c = 0; c < 2; ++c) {
        uint32_t a0 = pka[2 * c], a1 = pka[2 * c + 1];
        uint32_t b0 = pkb[2 * c], b1 = pkb[2 * c + 1];
        asm("v_permlane32_swap_b32 %0, %1" : "+v"(a0), "+v"(a1));
        asm("v_permlane32_swap_b32 %0, %1" : "+v"(b0), "+v"(b1));
        union { uint32_t u[4]; bf16x8 v; } pf;
        pf.u[0] = a0; pf.u[1] = b0; pf.u[2] = a1; pf.u[3] = b1;
        const int kap = rb * 2 + c;   // 16-key chunk within the 64-key tile
#pragma unroll
        for (int db = 0; db < 4; ++db)
          o_acc[db] = MFMA32(vv[kap * 4 + db], pf.v, o_acc[db]);
      }
    }
  }

  // epilogue: l reduce across the two key-halves (h pair), normalize, write O
  l_i += __shfl_xor(l_i, 32, 64);
  const float invl = 1.0f / l_i;
  const int q = q0 + wave * 32 + r31;
  bf16* orow = O + (size_t)(b * 2048 + q) * 2048 + (size_t)hd * 128;
#pragma unroll
  for (int db = 0; db < 4; ++db)
#pragma unroll
    for (int pp = 0; pp < 4; ++pp) {
      const int d0 = db * 32 + 8 * pp + 4 * h;
      bf16x4 o;
#pragma unroll
      for (int r = 0; r < 4; ++r) o[r] = (bf16)(o_acc[db][4 * pp + r] * invl);
      *(bf16x4*)(orow + d0) = o;
    }
}

extern "C" void kernel_launch(void* const* d_in, const int* in_sizes, int n_in,
                              void* d_out, int out_size, void* d_ws, size_t ws_size,
                              hipStream_t stream)
{
  (void)in_sizes; (void)n_in; (void)out_size; (void)ws_size;
  const float* x   = (const float*)d_in[0];
  const float* q_w = (const float*)d_in[1];
  const float* k_w = (const float*)d_in[2];
  const float* v_w = (const float*)d_in[3];
  const float* q_b = (const float*)d_in[4];
  const float* k_b = (const float*)d_in[5];
  const float* v_b = (const float*)d_in[6];
  const float* o_w = (const float*)d_in[7];
  const float* o_b = (const float*)d_in[8];

  const size_t NELEM = (size_t)MM * DM;   // 8388608
  const size_t WELEM = (size_t)DM * DM;   // 4194304
  bf16* Xb  = (bf16*)d_ws;                // reused as attnO (x dead by then)
  bf16* Wq  = Xb + NELEM;
  bf16* Wk  = Wq + WELEM;
  bf16* Wv  = Wk + WELEM;
  bf16* Wo  = Wv + WELEM;
  bf16* Q   = Wo + WELEM;
  bf16* Kb  = Q  + NELEM;
  bf16* Vt  = Kb + NELEM;
  bf16* attnO = Xb;

  cvt_f32_bf16<<<24576, 256, 0, stream>>>(x, q_w, k_w, v_w, o_w, Xb, Wq, Wk, Wv, Wo);

  gemm_qkv_fused<<<512, 256, 0, stream>>>(Xb, Wq, Wk, Wv, q_b, k_b, v_b, Q, Kb, Vt);
  attn<<<512, 256, 0, stream>>>(Q, Kb, Vt, attnO);
  gemm_bias_f32<<<512, 256, 0, stream>>>(attnO, Wo, o_b, (float*)d_out);
}

// Round 9
// 379.388 us; speedup vs baseline: 1.1202x; 1.1202x over previous
//
#include <hip/hip_runtime.h>
#include <stdint.h>

typedef __bf16 bf16;
typedef __bf16 bf16x4 __attribute__((ext_vector_type(4)));
typedef __bf16 bf16x8 __attribute__((ext_vector_type(8)));
typedef float f32x4 __attribute__((ext_vector_type(4)));
typedef float f32x16 __attribute__((ext_vector_type(16)));

#define DM 2048   // embed dim = N = K of GEMMs
#define MM 4096   // B*S rows
#define MFMA16(a, b, c) __builtin_amdgcn_mfma_f32_16x16x32_bf16(a, b, c, 0, 0, 0)
#define MFMA32(a, b, c) __builtin_amdgcn_mfma_f32_32x32x16_bf16(a, b, c, 0, 0, 0)

// counted-vmcnt barrier pair (T4): wait only the N newest-excluded loads.
#define WAITV_BAR(N) asm volatile("s_waitcnt vmcnt(" #N ")\n\ts_barrier" ::: "memory")
#define BAR()        asm volatile("s_barrier" ::: "memory")

__device__ __forceinline__ void gload_lds16(const void* g, void* l) {
  __builtin_amdgcn_global_load_lds((const __attribute__((address_space(1))) uint32_t*)g,
                                   (__attribute__((address_space(3))) uint32_t*)l, 16, 0, 0);
}

// fp32 -> bf16 for x (8.4M) and the 4 weight matrices (4.2M each).
__global__ __launch_bounds__(256) void cvt_f32_bf16(
    const float* __restrict__ s0, const float* __restrict__ s1,
    const float* __restrict__ s2, const float* __restrict__ s3,
    const float* __restrict__ s4,
    bf16* __restrict__ d0, bf16* __restrict__ d1, bf16* __restrict__ d2,
    bf16* __restrict__ d3, bf16* __restrict__ d4)
{
  const size_t i4 = (size_t)(blockIdx.x * 256 + threadIdx.x) * 4;  // float index
  const float* s; bf16* d; size_t off;
  if      (i4 <  8388608u) { s = s0; d = d0; off = i4;             }
  else if (i4 < 12582912u) { s = s1; d = d1; off = i4 -  8388608u; }
  else if (i4 < 16777216u) { s = s2; d = d2; off = i4 - 12582912u; }
  else if (i4 < 20971520u) { s = s3; d = d3; off = i4 - 16777216u; }
  else                     { s = s4; d = d4; off = i4 - 20971520u; }
  const float4 v = *(const float4*)(s + off);
  bf16x4 o = { (bf16)v.x, (bf16)v.y, (bf16)v.z, (bf16)v.w };
  *(bf16x4*)(d + off) = o;
}

// Fused QKV projection — R2 structure (proven 96 us, MfmaUtil 48%): BK=64,
// 2-barrier loop, XOR-swizzled LDS, A staged once for 96 MFMAs/k-step.
// RoPE + softmax-scale fused into Q/K epilogues. V written transposed.
// XCD swizzle: each XCD owns 2 n-columns (3 MB weights L2-resident).
__global__ __launch_bounds__(256, 2) void gemm_qkv_fused(
    const bf16* __restrict__ A,
    const bf16* __restrict__ Wq, const bf16* __restrict__ Wk, const bf16* __restrict__ Wv,
    const float* __restrict__ qb, const float* __restrict__ kb, const float* __restrict__ vb,
    bf16* __restrict__ Cq, bf16* __restrict__ Ck, bf16* __restrict__ Cv)
{
  __shared__ __align__(16) bf16 smem[32768];   // 64 KB
  bf16* As = smem;           // [128][64]
  bf16* Ws = smem + 8192;    // 3 x [128][64]

  const int id = blockIdx.x;               // 512 blocks
  const int xcd = id & 7, jj = id >> 3;
  const int n0 = (xcd * 2 + (jj >> 5)) * 128;
  const int m0 = (jj & 31) * 128;

  const int t = threadIdx.x;
  const int wave = t >> 6, lane = t & 63;
  const int quad = lane >> 4, c16 = lane & 15;
  const int wr = wave >> 1, wc = wave & 1;

  f32x4 acc[3][4][4] = {};

  // staging: granule g=rr*256+t -> LDS row=g>>3, slot=g&7; global column
  // granule = slot ^ (row&7)  (XOR swizzle; permutes within a 128B segment)
  const int srow = t >> 3;
  const int scol = ((t & 7) ^ (srow & 7)) * 8;
  const bf16* gA  = A  + (size_t)(m0 + srow) * DM + scol;
  const bf16* gW0 = Wq + (size_t)(n0 + srow) * DM + scol;
  const bf16* gW1 = Wk + (size_t)(n0 + srow) * DM + scol;
  const bf16* gW2 = Wv + (size_t)(n0 + srow) * DM + scol;

  for (int k0 = 0; k0 < DM; k0 += 64) {
#pragma unroll
    for (int rr = 0; rr < 4; ++rr) {
      const size_t go = (size_t)(rr * 32) * DM;
      const int lo = (rr * 256 + wave * 64) * 8;
      gload_lds16(gA  + go, As + lo);
      gload_lds16(gW0 + go, Ws + lo);
      gload_lds16(gW1 + go, Ws + 8192 + lo);
      gload_lds16(gW2 + go, Ws + 16384 + lo);
    }
    gA += 64; gW0 += 64; gW1 += 64; gW2 += 64;
    __syncthreads();

#pragma unroll
    for (int ks = 0; ks < 2; ++ks) {
      bf16x8 af[4];
#pragma unroll
      for (int i = 0; i < 4; ++i) {
        const int row = wr * 64 + i * 16 + c16;
        const int gi = (ks * 4 + quad) ^ (row & 7);
        af[i] = *(const bf16x8*)&As[row * 64 + gi * 8];
      }
#pragma unroll
      for (int z = 0; z < 3; ++z) {
        bf16x8 bfr[4];
#pragma unroll
        for (int jx = 0; jx < 4; ++jx) {
          const int row = wc * 64 + jx * 16 + c16;
          const int gi = (ks * 4 + quad) ^ (row & 7);
          bfr[jx] = *(const bf16x8*)&Ws[z * 8192 + row * 64 + gi * 8];
        }
#pragma unroll
        for (int i = 0; i < 4; ++i)
#pragma unroll
          for (int jx = 0; jx < 4; ++jx)
            acc[z][i][jx] = MFMA16(af[i], bfr[jx], acc[z][i][jx]);
      }
    }
    __syncthreads();
  }

  // ---- V epilogue: transposed to (B*H, Dh, S), bf16x4 along s ----
  const int h = n0 >> 7;   // one head per 128-wide n-column
#pragma unroll
  for (int jx = 0; jx < 4; ++jx) {
    const int d = wc * 64 + jx * 16 + c16;
    const float bv = vb[n0 + d];
#pragma unroll
    for (int i = 0; i < 4; ++i) {
      const int row = m0 + wr * 64 + i * 16 + quad * 4;
      const int b = row >> 11, s = row & 2047;
      bf16x4 o;
#pragma unroll
      for (int r = 0; r < 4; ++r) o[r] = (bf16)(acc[2][i][jx][r] + bv);
      *(bf16x4*)&Cv[((size_t)((b * 16 + h) * 128 + d)) * 2048 + s] = o;
    }
  }

  // ---- Q/K epilogues: bias + RoPE via LDS round-trip (pair d <-> d+64
  // crosses waves). Q additionally scaled by log2e/sqrt(Dh) for exp2 softmax.
  bf16* Tl = smem;  // [128][136], 34.8 KB, 16B-aligned rows
#pragma unroll
  for (int z = 0; z < 2; ++z) {
    __syncthreads();   // smem free (main loop done / previous z consumed)
#pragma unroll
    for (int jx = 0; jx < 4; ++jx) {
      const int col = wc * 64 + jx * 16 + c16;
      const float bv = (z == 0 ? qb : kb)[n0 + col];
#pragma unroll
      for (int i = 0; i < 4; ++i) {
        const int row = wr * 64 + i * 16 + quad * 4;
#pragma unroll
        for (int r = 0; r < 4; ++r)
          Tl[(row + r) * 136 + col] = (bf16)(acc[z][i][jx][r] + bv);
      }
    }
    __syncthreads();
    bf16* C = (z == 0) ? Cq : Ck;
    const float scale = (z == 0) ? 0.08838834764831845f * 1.4426950408889634f : 1.0f;
#pragma unroll
    for (int rr = 0; rr < 4; ++rr) {
      const int row = rr * 32 + (t >> 3);
      const int d0 = (t & 7) * 8;
      const int s = (m0 + row) & 2047;
      bf16x8 xa = *(const bf16x8*)&Tl[row * 136 + d0];
      bf16x8 xb = *(const bf16x8*)&Tl[row * 136 + d0 + 64];
      bf16x8 o1, o2;
#pragma unroll
      for (int j = 0; j < 8; ++j) {
        const float inv_freq = __expf((float)(d0 + j) * -0.14391156514261228f);
        float sn, cs;
        __sincosf((float)s * inv_freq, &sn, &cs);
        const float a = (float)xa[j], bb = (float)xb[j];
        o1[j] = (bf16)((a * cs - bb * sn) * scale);
        o2[j] = (bf16)((bb * cs + a * sn) * scale);
      }
      *(bf16x8*)&C[(size_t)(m0 + row) * DM + n0 + d0]      = o1;
      *(bf16x8*)&C[(size_t)(m0 + row) * DM + n0 + d0 + 64] = o2;
    }
  }
}

// Output projection GEMM + bias (fp32 out) — R2 structure (BK=64, 2-barrier).
__global__ __launch_bounds__(256, 2) void gemm_bias_f32(
    const bf16* __restrict__ A, const bf16* __restrict__ W,
    const float* __restrict__ bias, float* __restrict__ C)
{
  __shared__ __align__(16) bf16 As[8192];   // [128][64]
  __shared__ __align__(16) bf16 Bs[8192];
  const int id = blockIdx.x;               // 512 blocks
  const int xcd = id & 7, jj = id >> 3;
  const int n0 = (xcd * 2 + (jj >> 5)) * 128;
  const int m0 = (jj & 31) * 128;

  const int t = threadIdx.x;
  const int wave = t >> 6, lane = t & 63;
  const int quad = lane >> 4, c16 = lane & 15;
  const int wr = wave >> 1, wc = wave & 1;

  f32x4 acc[4][4] = {};
  const int srow = t >> 3;
  const int scol = ((t & 7) ^ (srow & 7)) * 8;
  const bf16* gA = A + (size_t)(m0 + srow) * DM + scol;
  const bf16* gB = W + (size_t)(n0 + srow) * DM + scol;

  for (int k0 = 0; k0 < DM; k0 += 64) {
#pragma unroll
    for (int rr = 0; rr < 4; ++rr) {
      const size_t go = (size_t)(rr * 32) * DM;
      const int lo = (rr * 256 + wave * 64) * 8;
      gload_lds16(gA + go, As + lo);
      gload_lds16(gB + go, Bs + lo);
    }
    gA += 64; gB += 64;
    __syncthreads();

#pragma unroll
    for (int ks = 0; ks < 2; ++ks) {
      bf16x8 af[4], bfr[4];
#pragma unroll
      for (int i = 0; i < 4; ++i) {
        const int row = wr * 64 + i * 16 + c16;
        const int gi = (ks * 4 + quad) ^ (row & 7);
        af[i] = *(const bf16x8*)&As[row * 64 + gi * 8];
      }
#pragma unroll
      for (int jx = 0; jx < 4; ++jx) {
        const int row = wc * 64 + jx * 16 + c16;
        const int gi = (ks * 4 + quad) ^ (row & 7);
        bfr[jx] = *(const bf16x8*)&Bs[row * 64 + gi * 8];
      }
#pragma unroll
      for (int i = 0; i < 4; ++i)
#pragma unroll
        for (int jx = 0; jx < 4; ++jx)
          acc[i][jx] = MFMA16(af[i], bfr[jx], acc[i][jx]);
    }
    __syncthreads();
  }

#pragma unroll
  for (int jx = 0; jx < 4; ++jx) {
    const int col = n0 + wc * 64 + jx * 16 + c16;
    const float bv = bias[col];
#pragma unroll
    for (int i = 0; i < 4; ++i) {
      const int row = m0 + wr * 64 + i * 16 + quad * 4;
#pragma unroll
      for (int r = 0; r < 4; ++r)
        C[(size_t)(row + r) * DM + col] = acc[i][jx][r] + bv;
    }
  }
}

// Flash attention v7b: in-block KEY-SPLIT + q-blocking for reuse=2 at full TLP.
// 4 waves: wave w -> q-rows (w&1)*64..+64 (QBLK=64: 2 qsub of 32) x keys
// (w>>1)*1024..+1024. Every kf/vf ds_read feeds 2 MFMAs; LDS instr count
// halves vs v3 while keeping grid 512 / 2 blocks/CU / 2 waves/SIMD.
// 32-key tile-sets per key-half, double-buffered: 2 kh x 2 buf x (8K K + 8K V)
// = 64 KB. Counted WAITV_BAR(8). No-max exp2 softmax => key-split combine is
// a pure sum: waves 2,3 pass unnormalized O (f32) + l through freed LDS in
// two phases; waves 0,1 add, normalize, write.
// v7b fix: gload_lds16 LDS dest made wave-uniform (HW adds lane*16B itself).
__global__ __launch_bounds__(256, 2) void attn(
    const bf16* __restrict__ Q, const bf16* __restrict__ K,
    const bf16* __restrict__ Vt, bf16* __restrict__ O)
{
  // layout (bf16 elements): K half kh buf nb at [kh*8192 + nb*4096] (32x128)
  //                         V half kh buf nb at [16384 + kh*8192 + nb*4096] (128x32)
  __shared__ __align__(16) bf16 smem[32768];   // 64 KB
  const int t = threadIdx.x;
  const int wave = t >> 6, lane = t & 63;
  const int r31 = lane & 31, h = lane >> 5;
  const int qg = wave & 1, kh = wave >> 1;
  const int id = blockIdx.x;               // 512 blocks
  const int xcd = id & 7, jj = id >> 3;
  const int bh = xcd * 4 + (jj >> 4);
  const int q0 = (jj & 15) * 128;
  const int b = bh >> 4, hd = bh & 15;

  // Q fragments (B-operand), 2 q-sub-blocks: lane holds Q[q][dh=ks*16+h*8+j]
  bf16x8 qf[2][8];
#pragma unroll
  for (int qs = 0; qs < 2; ++qs) {
    const bf16* qrow = Q + (size_t)(b * 2048 + q0 + qg * 64 + qs * 32 + r31) * 2048
                         + (size_t)hd * 128 + h * 8;
#pragma unroll
    for (int ks = 0; ks < 8; ++ks) qf[qs][ks] = *(const bf16x8*)(qrow + ks * 16);
  }

  float l_i[2] = {0.f, 0.f};
  f32x16 o_acc[2][4] = {};   // [qsub][db]: O^T[d=db*32+(reg&3)+8*(reg>>2)+4h][q=r31]

  const bf16* Kg = K + (size_t)(b * 2048) * 2048 + (size_t)hd * 128;
  const bf16* Vg = Vt + (size_t)bh * 128 * 2048;

  // stage ONE 32-key step for BOTH key-halves (32 KB): 8 gload_lds16/thread.
  // K: rows 256B, 16 granules, src col granule = gl ^ (key&7).
  // V: rows 64B, 4 granules, src col granule = gl ^ (d&3).  (G21 discipline.)
  // LDS dest is WAVE-UNIFORM (first granule of this wave's 64-granule chunk);
  // HW appends lane*16B.
  auto stage = [&](int it, int nb) {
#pragma unroll
    for (int j = 0; j < 4; ++j) {
      const int khs = j >> 1;                 // wave-uniform per j
      const int Gk = (j & 1) * 256 + t;       // 0..511 granule within half
      const int key = Gk >> 4, gl = Gk & 15;
      gload_lds16(Kg + (size_t)(khs * 1024 + it * 32 + key) * 2048 + ((gl ^ (key & 7)) * 8),
                  smem + khs * 8192 + nb * 4096 + ((j & 1) * 256 + wave * 64) * 8);
    }
#pragma unroll
    for (int j = 0; j < 4; ++j) {
      const int khs = j >> 1;
      const int Gq = (j & 1) * 256 + t;
      const int d = Gq >> 2, gl = Gq & 3;
      gload_lds16(Vg + (size_t)d * 2048 + khs * 1024 + it * 32 + ((gl ^ (d & 3)) * 8),
                  smem + 16384 + khs * 8192 + nb * 4096 + ((j & 1) * 256 + wave * 64) * 8);
    }
  };

  stage(0, 0);   // 8 loads in flight

  for (int it = 0; it < 32; ++it) {
    const int cb = it & 1;
    if (it < 31) {
      stage(it + 1, cb ^ 1);   // +8 loads; waited at iter it+1
      WAITV_BAR(8);
    } else {
      WAITV_BAR(0);
    }

    const bf16* KsB = smem + kh * 8192 + cb * 4096;           // [32][128]
    const bf16* VsB = smem + 16384 + kh * 8192 + cb * 4096;   // [128][32]

    // S^T[32 keys][32 q] for both q-sub-blocks; kf shared across qs (reuse=2)
    f32x16 st[2] = {};
#pragma unroll
    for (int ks = 0; ks < 8; ++ks) {
      const int g = (2 * ks + h) ^ (r31 & 7);
      bf16x8 kf = *(const bf16x8*)&KsB[r31 * 128 + g * 8];
      st[0] = MFMA32(kf, qf[0][ks], st[0]);
      st[1] = MFMA32(kf, qf[1][ks], st[1]);
    }

    // exp2 softmax (no max) + pack to PV B-fragments, per q-sub-block
    uint32_t pw[2][2][4];   // [qsub][16-key chunk][word]
#pragma unroll
    for (int qs = 0; qs < 2; ++qs) {
      float p[16];
#pragma unroll
      for (int r = 0; r < 16; ++r) { p[r] = exp2f(st[qs][r]); l_i[qs] += p[r]; }
      uint32_t pka[4], pkb[4];
#pragma unroll
      for (int pp = 0; pp < 4; ++pp) {
        asm("v_cvt_pk_bf16_f32 %0, %1, %2"
            : "=v"(pka[pp]) : "v"(p[4 * pp + 0]), "v"(p[4 * pp + 1]));
        asm("v_cvt_pk_bf16_f32 %0, %1, %2"
            : "=v"(pkb[pp]) : "v"(p[4 * pp + 2]), "v"(p[4 * pp + 3]));
      }
#pragma unroll
      for (int c = 0; c < 2; ++c) {
        uint32_t a0 = pka[2 * c], a1 = pka[2 * c + 1];
        uint32_t b0 = pkb[2 * c], b1 = pkb[2 * c + 1];
        asm("v_permlane32_swap_b32 %0, %1" : "+v"(a0), "+v"(a1));
        asm("v_permlane32_swap_b32 %0, %1" : "+v"(b0), "+v"(b1));
        pw[qs][c][0] = a0; pw[qs][c][1] = b0; pw[qs][c][2] = a1; pw[qs][c][3] = b1;
      }
    }

    // O^T += V^T P^T; vf shared across both q-sub-blocks (reuse=2)
#pragma unroll
    for (int c = 0; c < 2; ++c) {
      union { uint32_t u[4]; bf16x8 v; } p0, p1;
#pragma unroll
      for (int w2 = 0; w2 < 4; ++w2) { p0.u[w2] = pw[0][c][w2]; p1.u[w2] = pw[1][c][w2]; }
      const int g = (2 * c + h) ^ (r31 & 3);
#pragma unroll
      for (int db = 0; db < 4; ++db) {
        bf16x8 vf = *(const bf16x8*)&VsB[(db * 32 + r31) * 32 + g * 8];
        o_acc[0][db] = MFMA32(vf, p0.v, o_acc[0][db]);
        o_acc[1][db] = MFMA32(vf, p1.v, o_acc[1][db]);
      }
    }
    BAR();   // all waves done reading cb before iter it+1 DMA-writes it
  }

  // ---- epilogue: cross-wave key-half combine via LDS (2 serialized phases) --
  // wave-total l per q-row (combine the h partition within the wave first)
  float lw[2];
#pragma unroll
  for (int qs = 0; qs < 2; ++qs) lw[qs] = l_i[qs] + __shfl_xor(l_i[qs], 32, 64);

  float* fb = (float*)smem;      // o-partial region: 8192 floats (32 KB)
  float* lb = fb + 8192;         // l-exchange region: 128 floats

#pragma unroll
  for (int ph = 0; ph < 2; ++ph) {
    __syncthreads();             // previous phase (or main loop) fully drained
    if (wave == 2 + ph) {        // kh=1 wave of q-group ph: publish partials
#pragma unroll
      for (int qs = 0; qs < 2; ++qs) {
#pragma unroll
        for (int db = 0; db < 4; ++db)
#pragma unroll
          for (int pp = 0; pp < 4; ++pp) {
            float4 v = { o_acc[qs][db][4 * pp + 0], o_acc[qs][db][4 * pp + 1],
                         o_acc[qs][db][4 * pp + 2], o_acc[qs][db][4 * pp + 3] };
            *(float4*)&fb[lane * 128 + qs * 64 + db * 16 + pp * 4] = v;
          }
        lb[lane * 2 + qs] = lw[qs];
      }
    }
    __syncthreads();
    if (wave == ph) {            // kh=0 wave of q-group ph: combine + write O
#pragma unroll
      for (int qs = 0; qs < 2; ++qs) {
        const float l = lw[qs] + lb[lane * 2 + qs];
        const float invl = 1.0f / l;
        const int q = q0 + ph * 64 + qs * 32 + r31;
        bf16* orow = O + (size_t)(b * 2048 + q) * 2048 + (size_t)hd * 128;
#pragma unroll
        for (int db = 0; db < 4; ++db)
#pragma unroll
          for (int pp = 0; pp < 4; ++pp) {
            float4 v = *(const float4*)&fb[lane * 128 + qs * 64 + db * 16 + pp * 4];
            const int d0 = db * 32 + 8 * pp + 4 * h;
            bf16x4 o;
            o[0] = (bf16)((o_acc[qs][db][4 * pp + 0] + v.x) * invl);
            o[1] = (bf16)((o_acc[qs][db][4 * pp + 1] + v.y) * invl);
            o[2] = (bf16)((o_acc[qs][db][4 * pp + 2] + v.z) * invl);
            o[3] = (bf16)((o_acc[qs][db][4 * pp + 3] + v.w) * invl);
            *(bf16x4*)(orow + d0) = o;
          }
      }
    }
  }
}

extern "C" void kernel_launch(void* const* d_in, const int* in_sizes, int n_in,
                              void* d_out, int out_size, void* d_ws, size_t ws_size,
                              hipStream_t stream)
{
  (void)in_sizes; (void)n_in; (void)out_size; (void)ws_size;
  const float* x   = (const float*)d_in[0];
  const float* q_w = (const float*)d_in[1];
  const float* k_w = (const float*)d_in[2];
  const float* v_w = (const float*)d_in[3];
  const float* q_b = (const float*)d_in[4];
  const float* k_b = (const float*)d_in[5];
  const float* v_b = (const float*)d_in[6];
  const float* o_w = (const float*)d_in[7];
  const float* o_b = (const float*)d_in[8];

  const size_t NELEM = (size_t)MM * DM;   // 8388608
  const size_t WELEM = (size_t)DM * DM;   // 4194304
  bf16* Xb  = (bf16*)d_ws;                // reused as attnO (x dead by then)
  bf16* Wq  = Xb + NELEM;
  bf16* Wk  = Wq + WELEM;
  bf16* Wv  = Wk + WELEM;
  bf16* Wo  = Wv + WELEM;
  bf16* Q   = Wo + WELEM;
  bf16* Kb  = Q  + NELEM;
  bf16* Vt  = Kb + NELEM;
  bf16* attnO = Xb;

  cvt_f32_bf16<<<24576, 256, 0, stream>>>(x, q_w, k_w, v_w, o_w, Xb, Wq, Wk, Wv, Wo);

  gemm_qkv_fused<<<512, 256, 0, stream>>>(Xb, Wq, Wk, Wv, q_b, k_b, v_b, Q, Kb, Vt);
  attn<<<512, 256, 0, stream>>>(Q, Kb, Vt, attnO);
  gemm_bias_f32<<<512, 256, 0, stream>>>(attnO, Wo, o_b, (float*)d_out);
}